// Round 10
// baseline (1492.172 us; speedup 1.0000x reference)
//
#include <hip/hip_runtime.h>

typedef short bf16x8 __attribute__((ext_vector_type(8)));
typedef short short4v __attribute__((ext_vector_type(4)));
typedef float f32x4 __attribute__((ext_vector_type(4)));

#define SCALE_ATTN 0.08838834764831845f

__device__ inline short f2bs(float f) {
    unsigned u = __builtin_bit_cast(unsigned, f);
    unsigned r = (u + 0x7fffu + ((u >> 16) & 1u)) >> 16;
    return (short)(unsigned short)r;
}
__device__ inline float b2f(short s) {
    unsigned u = ((unsigned)(unsigned short)s) << 16;
    return __builtin_bit_cast(float, u);
}
__device__ inline void pack_w4(const f32x4& a, const f32x4& b, bf16x8& p) {
    p[0] = f2bs(a[0]); p[1] = f2bs(a[1]); p[2] = f2bs(a[2]); p[3] = f2bs(a[3]);
    p[4] = f2bs(b[0]); p[5] = f2bs(b[1]); p[6] = f2bs(b[2]); p[7] = f2bs(b[3]);
}

// ---------------------------------------------------------------------------
// weight convert f32 -> bf16 (RNE), grid-stride.  Grid-stride shape drains
// its own writes within its window (R3/R8 clean); one-shot burst shapes leave
// ~224 MiB dirty in L3 that drains inside the NEXT GEMM (R5/R7/R9, +130 us).
// ---------------------------------------------------------------------------
__global__ __launch_bounds__(256)
void wconv_kernel(const float* __restrict__ src, short* __restrict__ dst, long n8)
{
    const long stride = (long)gridDim.x << 8;
    for (long i = ((long)blockIdx.x << 8) + threadIdx.x; i < n8; i += stride) {
        const f32x4 a = __builtin_nontemporal_load(&((const f32x4*)src)[i << 1]);
        const f32x4 b = __builtin_nontemporal_load(&((const f32x4*)src)[(i << 1) + 1]);
        bf16x8 p;
        pack_w4(a, b, p);
        __builtin_nontemporal_store(p, &((bf16x8*)dst)[i]);
    }
}

// ---------------------------------------------------------------------------
// gate_up weight convert + permute, GRID-STRIDE (drain-safe shape).
// Output row n <- orig gate row t*128+r (r<128) or up row 14336+t*128+(r-128),
// t=n>>8, r=n&255.  512 8-elem groups per row.
// ---------------------------------------------------------------------------
__global__ __launch_bounds__(256)
void wconv_gu_kernel(const float* __restrict__ src, short* __restrict__ dst)
{
    const long n8 = 14680064L;
    const long stride = (long)gridDim.x << 8;
    for (long i = ((long)blockIdx.x << 8) + threadIdx.x; i < n8; i += stride) {
        const int n = (int)(i >> 9);
        const int j = (int)(i & 511);
        const int t = n >> 8, r = n & 255;
        const int orig = (r < 128) ? (t * 128 + r) : (14336 + t * 128 + (r - 128));
        const long s = ((long)orig << 9) + j;
        const f32x4 a = __builtin_nontemporal_load(&((const f32x4*)src)[s << 1]);
        const f32x4 b = __builtin_nontemporal_load(&((const f32x4*)src)[(s << 1) + 1]);
        bf16x8 p;
        pack_w4(a, b, p);
        __builtin_nontemporal_store(p, &((bf16x8*)dst)[i]);
    }
}

// ---------------------------------------------------------------------------
// fused (X [+X2] [+Rin]) -> Rout(f32), rmsnorm -> Hout(bf16). 1 block/row.
// ---------------------------------------------------------------------------
__global__ __launch_bounds__(256)
void add_rmsnorm_kernel(const float* __restrict__ X, const float* __restrict__ X2,
                        const float* __restrict__ Rin, const float* __restrict__ w,
                        float* __restrict__ Rout, short* __restrict__ Hout)
{
    const int tid = threadIdx.x;
    const long base = (long)blockIdx.x << 12;
    float v[16];
    float ss = 0.f;
#pragma unroll
    for (int p = 0; p < 4; ++p) {
        const int idx = (p << 10) + (tid << 2);
        f32x4 a = *(const f32x4*)(X + base + idx);
        if (X2 != nullptr) {
            f32x4 b = *(const f32x4*)(X2 + base + idx);
            a += b;
        }
        if (Rin != nullptr) {
            f32x4 b = *(const f32x4*)(Rin + base + idx);
            a += b;
        }
        v[p*4+0] = a[0]; v[p*4+1] = a[1]; v[p*4+2] = a[2]; v[p*4+3] = a[3];
        ss += a[0]*a[0] + a[1]*a[1] + a[2]*a[2] + a[3]*a[3];
    }
#pragma unroll
    for (int dd = 1; dd < 64; dd <<= 1) ss += __shfl_xor(ss, dd);
    __shared__ float red[4];
    if ((tid & 63) == 0) red[tid >> 6] = ss;
    __syncthreads();
    const float tot = red[0] + red[1] + red[2] + red[3];
    const float rstd = rsqrtf(tot * (1.0f / 4096.0f) + 1e-5f);
#pragma unroll
    for (int p = 0; p < 4; ++p) {
        const int idx = (p << 10) + (tid << 2);
        if (Rout != nullptr) {
            f32x4 b;
            b[0] = v[p*4+0]; b[1] = v[p*4+1]; b[2] = v[p*4+2]; b[3] = v[p*4+3];
            *(f32x4*)(Rout + base + idx) = b;
        }
        f32x4 wv4 = *(const f32x4*)(w + idx);
        short4v hb;
        hb[0] = f2bs(v[p*4+0] * rstd * wv4[0]);
        hb[1] = f2bs(v[p*4+1] * rstd * wv4[1]);
        hb[2] = f2bs(v[p*4+2] * rstd * wv4[2]);
        hb[3] = f2bs(v[p*4+3] * rstd * wv4[3]);
        *(short4v*)(Hout + base + idx) = hb;
    }
}

// ---------------------------------------------------------------------------
// out = a + b (f32)
// ---------------------------------------------------------------------------
__global__ __launch_bounds__(256)
void add2_kernel(const float* __restrict__ a, const float* __restrict__ b,
                 float* __restrict__ o, long n4)
{
    const long st = (long)gridDim.x << 8;
    for (long i = ((long)blockIdx.x << 8) + threadIdx.x; i < n4; i += st) {
        f32x4 x = __builtin_nontemporal_load(&((const f32x4*)a)[i]);
        f32x4 y = __builtin_nontemporal_load(&((const f32x4*)b)[i]);
        x += y;
        ((f32x4*)o)[i] = x;
    }
}

// ===========================================================================
// 8-phase 256x256 GEMM (R3-proven body), XCD swizzle, optional 2-way K-split.
// EPI 0: f32 store (+KS partial offset).  EPI 3: fused silu(gate)*up -> bf16
// (permuted weights; eps stride 260 f32 -> 2-way bank alias = free).
// ===========================================================================
#define BAR()   do { asm volatile("" ::: "memory"); __builtin_amdgcn_s_barrier(); asm volatile("" ::: "memory"); } while (0)
#define LGKM0() asm volatile("s_waitcnt lgkmcnt(0)" ::: "memory")
#define VMW(n)  asm volatile("s_waitcnt vmcnt(" #n ")" ::: "memory")

__device__ inline bf16x8 lds_frag(const short* tile, int row, int kb) {
    const int off = row * 128 + (kb ^ ((row & 7) << 4));
    return *(const bf16x8*)((const char*)tile + off);
}

// stage one half-tile (128 rows x 64 k): linear LDS dest, inverse-swizzled src
__device__ inline void stage_half(const short* __restrict__ G, long grow0, long K,
                                  long k0, short* ldsHalf, int wv, int lane)
{
#pragma unroll
    for (int i = 0; i < 2; ++i) {
        short* dst = ldsHalf + ((i << 13) + (wv << 10)) / 2;   // wave-uniform
        const int off = (wv << 10) + (i << 13) + (lane << 4);  // lane's byte slot
        const int r   = off >> 7;
        const int cb  = off & 127;
        const int gcb = cb ^ ((r & 7) << 4);
        const short* src = G + (grow0 + r) * K + k0 + (gcb >> 1);
        __builtin_amdgcn_global_load_lds(
            (const __attribute__((address_space(1))) void*)(const void*)src,
            (__attribute__((address_space(3))) void*)(void*)dst, 16, 0, 0);
    }
}

#define LOAD_A(T, grp) do {                                        \
    _Pragma("unroll") for (int _m = 0; _m < 4; ++_m) {             \
        const int _row = abase + (grp)*64 + _m*16 + l15;           \
        a[_m][0] = lds_frag(T, _row, l4b);                         \
        a[_m][1] = lds_frag(T, _row, 64 + l4b);                    \
    } } while (0)

#define LOAD_B(T, n0) do {                                         \
    _Pragma("unroll") for (int _n = 0; _n < 2; ++_n) {             \
        const int _row = bbase + ((n0)+_n)*16 + l15;               \
        b[(n0)+_n][0] = lds_frag(T, _row, l4b);                    \
        b[(n0)+_n][1] = lds_frag(T, _row, 64 + l4b);               \
    } } while (0)

#define MFMA16(MB, NB) do {                                                        \
    __builtin_amdgcn_s_setprio(1);                                                 \
    _Pragma("unroll") for (int _m = 0; _m < 4; ++_m)                               \
    _Pragma("unroll") for (int _n = 0; _n < 2; ++_n) {                             \
        acc[(MB)+_m][(NB)+_n] = __builtin_amdgcn_mfma_f32_16x16x32_bf16(           \
            a[_m][0], b[(NB)+_n][0], acc[(MB)+_m][(NB)+_n], 0, 0, 0);              \
        acc[(MB)+_m][(NB)+_n] = __builtin_amdgcn_mfma_f32_16x16x32_bf16(           \
            a[_m][1], b[(NB)+_n][1], acc[(MB)+_m][(NB)+_n], 0, 0, 0);              \
    }                                                                              \
    __builtin_amdgcn_s_setprio(0);                                                 \
} while (0)

template<int EPI, int KS>
__global__ __launch_bounds__(512, 2)
void gemm8(const short* __restrict__ A, const short* __restrict__ W,
           float* __restrict__ Cf, short* __restrict__ Cb,
           int N, int K)
{
    __shared__ __align__(16) short As[2][16384];
    __shared__ __align__(16) short Bs[2][16384];

    const int tid  = threadIdx.x;
    const int lane = tid & 63;
    const int wv   = tid >> 6;
    const int wm   = wv >> 2;
    const int wn   = wv & 3;
    const int l15  = lane & 15;
    const int l4b  = (lane >> 4) << 4;

    // XCD swizzle; within an XCD: 8 consecutive blocks share one (bx,kz) panel
    const int gx   = gridDim.x;
    const int nwg  = gx * 8 * KS;
    const int cpx  = nwg >> 3;
    const int orig = (blockIdx.z * 8 + blockIdx.y) * gx + blockIdx.x;
    const int lgc  = (orig & 7) * cpx + (orig >> 3);
    const int by   = lgc & 7;
    const int tq   = lgc >> 3;
    const int kz   = (KS == 1) ? 0 : (tq % KS);
    const int bx   = (KS == 1) ? tq : (tq / KS);

    const long row0 = (long)by << 8;
    const long col0 = (long)bx << 8;
    const int abase = wm << 7;
    const int bbase = wn << 6;

    const int  Kc    = K / KS;
    const long kbase = (long)kz * Kc;
    const int  iters = Kc >> 7;

    f32x4 acc[8][4];
#pragma unroll
    for (int i = 0; i < 8; ++i)
#pragma unroll
        for (int j = 0; j < 4; ++j) acc[i][j] = (f32x4){0.f,0.f,0.f,0.f};

    bf16x8 a[4][2], b[4][2];

    // prologue: stage buf0 (tile0) then buf1 (tile1)
    stage_half(A, row0,       K, kbase,      &As[0][0],    wv, lane);
    stage_half(A, row0 + 128, K, kbase,      &As[0][8192], wv, lane);
    stage_half(W, col0,       K, kbase,      &Bs[0][0],    wv, lane);
    stage_half(W, col0 + 128, K, kbase,      &Bs[0][8192], wv, lane);
    stage_half(A, row0,       K, kbase + 64, &As[1][0],    wv, lane);
    stage_half(A, row0 + 128, K, kbase + 64, &As[1][8192], wv, lane);
    stage_half(W, col0,       K, kbase + 64, &Bs[1][0],    wv, lane);
    stage_half(W, col0 + 128, K, kbase + 64, &Bs[1][8192], wv, lane);
    VMW(8);
    BAR();

#pragma unroll 1
    for (int it = 0; it < iters; ++it) {
        const long k2 = kbase + ((long)(2*it + 2) << 6);
        const long k3 = k2 + 64;
        const bool pf = (it + 1 < iters);

        // ---------------- tile 2it (buf0) ----------------
        // P1
        LOAD_A(As[0], 0); LOAD_B(Bs[0], 0);
        BAR(); LGKM0(); MFMA16(0, 0); BAR();
        // P2
        LOAD_B(Bs[0], 2);
        BAR(); LGKM0(); MFMA16(0, 2); BAR();
        // P3
        LOAD_A(As[0], 1);
        if (pf) stage_half(W, col0, K, k2, &Bs[0][0], wv, lane);
        BAR(); LGKM0(); MFMA16(4, 0); BAR();
        // P4
        if (pf) {
            stage_half(A, row0,       K, k2, &As[0][0],    wv, lane);
            stage_half(W, col0 + 128, K, k2, &Bs[0][8192], wv, lane);
        }
        VMW(6);
        BAR(); MFMA16(4, 2); BAR();

        // ---------------- tile 2it+1 (buf1) ----------------
        // P5
        LOAD_A(As[1], 0); LOAD_B(Bs[1], 0);
        if (pf) stage_half(A, row0 + 128, K, k2, &As[0][8192], wv, lane);
        BAR(); LGKM0(); MFMA16(0, 0); BAR();
        // P6
        LOAD_B(Bs[1], 2);
        BAR(); LGKM0(); MFMA16(0, 2); BAR();
        // P7
        LOAD_A(As[1], 1);
        if (pf) {
            stage_half(W, col0,       K, k3, &Bs[1][0],    wv, lane);
            stage_half(W, col0 + 128, K, k3, &Bs[1][8192], wv, lane);
        }
        BAR(); LGKM0(); MFMA16(4, 0); BAR();
        // P8
        if (pf) {
            stage_half(A, row0,       K, k3, &As[1][0],    wv, lane);
            stage_half(A, row0 + 128, K, k3, &As[1][8192], wv, lane);
        }
        VMW(8);
        BAR(); MFMA16(4, 2); BAR();
    }

    if (EPI == 0) {
        float* Cfp = Cf + ((KS > 1) ? (long)kz * ((long)N << 11) : 0);
#pragma unroll
        for (int m = 0; m < 8; ++m) {
#pragma unroll
            for (int n = 0; n < 4; ++n) {
                const long gr = row0 + (wm << 7) + m*16 + ((lane >> 4) << 2);
                const long gc = col0 + (wn << 6) + n*16 + l15;
#pragma unroll
                for (int r = 0; r < 4; ++r)
                    Cfp[(gr + r) * N + gc] = acc[m][n][r];
            }
        }
    } else {
        // EPI 3: fused silu(gate)*up.  256 W-cols = 128 gate + 128 matching
        // up rows (permuted weights); combine via LDS, write bf16 hm[2048][N].
        // eps stride 260 f32: 4*260 mod 32 = 16 -> 2-way alias (free, m136).
        float* eps = (float*)&As[0][0];            // 32 x 260 f32 = 33.3 KB
        const int r4 = (lane >> 4) << 2;
        const int rr = tid >> 4;                   // 0..31
        const int cc = (tid & 15) << 3;            // 0..120
#pragma unroll 1
        for (int m = 0; m < 8; ++m) {
            __syncthreads();
#pragma unroll
            for (int n = 0; n < 4; ++n)
#pragma unroll
                for (int r = 0; r < 4; ++r)
                    eps[(wm*16 + r4 + r)*260 + (wn << 6) + n*16 + l15] = acc[m][n][r];
            __syncthreads();
            const float* rowp = eps + rr * 260;
            bf16x8 ov;
#pragma unroll
            for (int e = 0; e < 8; ++e) {
                const float g = rowp[cc + e];
                const float u = rowp[cc + 128 + e];
                ov[e] = f2bs(g / (1.f + __expf(-g)) * u);
            }
            const long grow = row0 + ((rr >> 4) << 7) + m*16 + (rr & 15);
            *(bf16x8*)(Cb + grow * N + (col0 >> 1) + cc) = ov;
        }
    }
}

// ---------------------------------------------------------------------------
// RoPE (reads 2 K-split partials of qkv f32 and sums)
// ---------------------------------------------------------------------------
__global__ __launch_bounds__(128)
void rope_kernel(const int* __restrict__ pos, const float* __restrict__ q0p,
                 const float* __restrict__ q1p,
                 short* __restrict__ Qo, short* __restrict__ Ko)
{
    const int h = blockIdx.x;
    const int s = blockIdx.y;
    const int d = threadIdx.x;
    const int j = d & 63;
    const float p = (float)pos[s];
    const float invf = __expf((float)j * -0.20503692895f);  // ln(5e5)/64
    float sn, cs;
    __sincosf(p * invf, &sn, &cs);
    const long base = (long)s * 6144 + h * 128;
    const float x1 = q0p[base + j] + q1p[base + j];
    const float x2 = q0p[base + 64 + j] + q1p[base + 64 + j];
    const float outv = (d < 64) ? (x1 * cs - x2 * sn) : (x2 * cs + x1 * sn);
    const short ob = f2bs(outv);
    if (h < 32) Qo[(long)s * 4096 + h * 128 + d] = ob;
    else        Ko[(long)s * 1024 + (h - 32) * 128 + d] = ob;
}

// ---------------------------------------------------------------------------
// V transpose: qkv partials f32 v-part [S,8,128] -> Vt bf16 [8][128][S]
// ---------------------------------------------------------------------------
__global__ __launch_bounds__(256)
void vtrans_kernel(const float* __restrict__ q0p, const float* __restrict__ q1p,
                   short* __restrict__ Vt)
{
    __shared__ short tile[64][136];
    const int tid = threadIdx.x;
    const int s0 = blockIdx.x << 6;
    const int h = blockIdx.y;
    {
        const int srow = tid >> 2;
        const int c0 = (tid & 3) << 5;
        const long off = (long)(s0 + srow) * 6144 + 5120 + h * 128 + c0;
#pragma unroll
        for (int m = 0; m < 8; ++m) {
            f32x4 f = *(const f32x4*)(q0p + off + (m << 2));
            f32x4 g = *(const f32x4*)(q1p + off + (m << 2));
            f += g;
            tile[srow][c0 + (m << 2) + 0] = f2bs(f[0]);
            tile[srow][c0 + (m << 2) + 1] = f2bs(f[1]);
            tile[srow][c0 + (m << 2) + 2] = f2bs(f[2]);
            tile[srow][c0 + (m << 2) + 3] = f2bs(f[3]);
        }
    }
    __syncthreads();
    {
        const int d = tid >> 1;
        const int sc = (tid & 1) << 5;
        short* dst = Vt + ((long)h * 128 + d) * 2048 + s0 + sc;
#pragma unroll
        for (int m = 0; m < 4; ++m) {
            bf16x8 v;
#pragma unroll
            for (int e = 0; e < 8; ++e) v[e] = tile[sc + (m << 3) + e][d];
            *(bf16x8*)(dst + (m << 3)) = v;
        }
    }
}

// ---------------------------------------------------------------------------
// Flash attention (causal, GQA rep=4)
// ---------------------------------------------------------------------------
__global__ __launch_bounds__(256)
void flash_kernel(const short* __restrict__ Qg, const short* __restrict__ Kg,
                  const short* __restrict__ Vtg, short* __restrict__ Ctx)
{
    __shared__ short Qs[64 * 128];
    __shared__ short Ks[64 * 128];
    __shared__ short Vs[128 * 64];
    __shared__ short Ps[4 * 16 * 64];

    const int tid  = threadIdx.x;
    const int lane = tid & 63;
    const int wv   = tid >> 6;
    const int l15  = lane & 15;
    const int l4e  = (lane >> 4) << 3;
    const int qt   = blockIdx.x;
    const int head = blockIdx.y;
    const int q0   = qt << 6;
    const int kvh  = head >> 2;

    {   // stage Q (swizzled)
        const int row = tid >> 2;
        const int c0 = (tid & 3) << 5;
        const short* src = Qg + (long)(q0 + row) * 4096 + head * 128 + c0;
        const int sw = (row & 7) << 3;
#pragma unroll
        for (int m = 0; m < 4; ++m) {
            bf16x8 v = *(const bf16x8*)(src + (m << 3));
            *(bf16x8*)&Qs[row * 128 + ((c0 + (m << 3)) ^ sw)] = v;
        }
    }

    float mrow[4], lrow[4];
    f32x4 o[8];
#pragma unroll
    for (int r = 0; r < 4; ++r) { mrow[r] = -__builtin_inff(); lrow[r] = 0.f; }
#pragma unroll
    for (int d = 0; d < 8; ++d) o[d] = (f32x4){0.f,0.f,0.f,0.f};

    for (int t = 0; t <= qt; ++t) {
        const int kv0 = t << 6;
        __syncthreads();
        {   // stage K
            const int row = tid >> 2;
            const int c0 = (tid & 3) << 5;
            const short* src = Kg + (long)(kv0 + row) * 1024 + kvh * 128 + c0;
            const int sw = (row & 7) << 3;
#pragma unroll
            for (int m = 0; m < 4; ++m) {
                bf16x8 v = *(const bf16x8*)(src + (m << 3));
                *(bf16x8*)&Ks[row * 128 + ((c0 + (m << 3)) ^ sw)] = v;
            }
        }
        {   // stage Vt
            const int d = tid >> 1;
            const int c0 = (tid & 1) << 5;
            const short* src = Vtg + ((long)kvh * 128 + d) * 2048 + kv0 + c0;
            const int sw = (d & 7) << 3;
#pragma unroll
            for (int m = 0; m < 4; ++m) {
                bf16x8 v = *(const bf16x8*)(src + (m << 3));
                *(bf16x8*)&Vs[d * 64 + ((c0 + (m << 3)) ^ sw)] = v;
            }
        }
        __syncthreads();

        bf16x8 qa[4];
        {
            const int qrow = (wv << 4) + l15;
            const int sw = (qrow & 7) << 3;
#pragma unroll
            for (int kk = 0; kk < 4; ++kk)
                qa[kk] = *(const bf16x8*)&Qs[qrow * 128 + ((l4e + (kk << 5)) ^ sw)];
        }
        f32x4 sacc[4];
#pragma unroll
        for (int j = 0; j < 4; ++j) {
            sacc[j] = (f32x4){0.f,0.f,0.f,0.f};
            const int krow = (j << 4) + l15;
            const int sw = (krow & 7) << 3;
#pragma unroll
            for (int kk = 0; kk < 4; ++kk) {
                bf16x8 kb8 = *(const bf16x8*)&Ks[krow * 128 + ((l4e + (kk << 5)) ^ sw)];
                sacc[j] = __builtin_amdgcn_mfma_f32_16x16x32_bf16(qa[kk], kb8, sacc[j], 0, 0, 0);
            }
        }

#pragma unroll
        for (int ri = 0; ri < 4; ++ri) {
            const int grow = q0 + (wv << 4) + ((lane >> 4) << 2) + ri;
            float sv[4];
#pragma unroll
            for (int j = 0; j < 4; ++j) {
                float s = sacc[j][ri] * SCALE_ATTN;
                const int col = kv0 + (j << 4) + l15;
                sv[j] = (col > grow) ? -1e30f : s;
            }
            float mx = fmaxf(fmaxf(sv[0], sv[1]), fmaxf(sv[2], sv[3]));
#pragma unroll
            for (int dd = 1; dd < 16; dd <<= 1) mx = fmaxf(mx, __shfl_xor(mx, dd));
            const float mnew = fmaxf(mrow[ri], mx);
            const float alpha = __expf(mrow[ri] - mnew);
            mrow[ri] = mnew;
            float psum = 0.f;
            short pb[4];
#pragma unroll
            for (int j = 0; j < 4; ++j) {
                float p = __expf(sv[j] - mnew);
                psum += p;
                pb[j] = f2bs(p);
            }
            lrow[ri] = lrow[ri] * alpha + psum;
#pragma unroll
            for (int d = 0; d < 8; ++d) o[d][ri] *= alpha;
            const int prow = ((lane >> 4) << 2) + ri;
            const int sw = (prow & 7) << 3;
#pragma unroll
            for (int j = 0; j < 4; ++j)
                Ps[(wv << 10) + prow * 64 + ((((j << 4) + l15)) ^ sw)] = pb[j];
        }

        bf16x8 pa0, pa1;
        {
            const int prow = l15;
            const int sw = (prow & 7) << 3;
            pa0 = *(const bf16x8*)&Ps[(wv << 10) + prow * 64 + (l4e ^ sw)];
            pa1 = *(const bf16x8*)&Ps[(wv << 10) + prow * 64 + ((l4e + 32) ^ sw)];
        }
#pragma unroll
        for (int fd = 0; fd < 8; ++fd) {
            const int drow = (fd << 4) + l15;
            const int sw = (drow & 7) << 3;
            bf16x8 v0 = *(const bf16x8*)&Vs[drow * 64 + (l4e ^ sw)];
            bf16x8 v1 = *(const bf16x8*)&Vs[drow * 64 + ((l4e + 32) ^ sw)];
            o[fd] = __builtin_amdgcn_mfma_f32_16x16x32_bf16(pa0, v0, o[fd], 0, 0, 0);
            o[fd] = __builtin_amdgcn_mfma_f32_16x16x32_bf16(pa1, v1, o[fd], 0, 0, 0);
        }
    }

    float inv[4];
#pragma unroll
    for (int ri = 0; ri < 4; ++ri) {
        float ls = lrow[ri];
#pragma unroll
        for (int dd = 1; dd < 16; dd <<= 1) ls += __shfl_xor(ls, dd);
        inv[ri] = 1.0f / ls;
    }
#pragma unroll
    for (int fd = 0; fd < 8; ++fd)
#pragma unroll
        for (int ri = 0; ri < 4; ++ri) {
            const long row = q0 + (wv << 4) + ((lane >> 4) << 2) + ri;
            Ctx[row * 4096 + head * 128 + (fd << 4) + l15] = f2bs(o[fd][ri] * inv[ri]);
        }
}

// ---------------------------------------------------------------------------
extern "C" void kernel_launch(void* const* d_in, const int* in_sizes, int n_in,
                              void* d_out, int out_size, void* d_ws, size_t ws_size,
                              hipStream_t stream)
{
    const int*   positions = (const int*)d_in[0];
    const float* hidden    = (const float*)d_in[1];
    const float* residual  = (const float*)d_in[2];
    const float* w_qkv     = (const float*)d_in[3];
    const float* w_o       = (const float*)d_in[4];
    const float* w_gu      = (const float*)d_in[5];
    const float* w_down    = (const float*)d_in[6];
    const float* w_ln1     = (const float*)d_in[7];
    const float* w_ln2     = (const float*)d_in[8];

    float* out_f   = (float*)d_out;              // [2048,4096] final output
    float* resid2  = out_f + 8388608;            // [2048,4096] residual output
    float* resid1  = out_f;                      // scratch: dead before add2 writes

    char* wsb = (char*)d_ws;
    short* h1     = (short*)(wsb + 0);           // 16.8 MB (dead after qkv gemm)
    short* ctx    = (short*)(wsb + 0);           // reuse (dead after o gemm)
    float* qkvp0  = (float*)(wsb + 16777216);    // 50.3 MB partial 0 (dead after rope/vtrans)
    float* qkvp1  = (float*)(wsb + 67108864);    // 50.3 MB partial 1 (dead after rope/vtrans)
    short* h2     = (short*)(wsb + 16777216);    // reuse (16.8 MB, dead after gate_up)
    float* Po     = (float*)(wsb + 33554432);    // 2x33.5 MB o partials (33.5..100.7, dead after rms2)
    short* hm     = (short*)(wsb + 33554432);    // 58.7 MB (over dead Po, written in gate_up)
    short* qb     = (short*)(wsb + 117440512);   // 16.8 MB (dead after flash)
    short* kb     = (short*)(wsb + 134217728);   //  4.2 MB (dead after flash)
    short* vt     = (short*)(wsb + 138412032);   //  4.2 MB (dead after flash)
    short* wbuf_o = (short*)(wsb + 150994944);   // 33.5 MB o-weights (144..177.5, dead after o gemm)
    float* Pd     = (float*)(wsb + 117440512);   // 2x33.5 MB down partials (112..179, qb..wbuf_o dead)
    short* wbuf   = (short*)(wsb + 209715200);   // 235 MB bf16 weight slab

    // 1. residual1 = hidden + residual ; h1 = rmsnorm(residual1)
    add_rmsnorm_kernel<<<2048, 256, 0, stream>>>(hidden, nullptr, residual, w_ln1, resid1, h1);
    // 2. qkv (2-way K-split partials; summed inside rope/vtrans)
    wconv_kernel<<<2048, 256, 0, stream>>>(w_qkv, wbuf, 3145728L);
    gemm8<0,2><<<dim3(24, 8, 2), 512, 0, stream>>>(h1, wbuf, qkvp0, nullptr, 6144, 4096);
    // 3. gate_up weights EARLY (grid-stride, permuted): ~300us of light kernels
    //    follow before gate_up GEMM reads the slab -> drain completes, slab warm.
    wconv_gu_kernel<<<2048, 256, 0, stream>>>(w_gu, wbuf);
    // 4. o weights (separate region, also early)
    wconv_kernel<<<2048, 256, 0, stream>>>(w_o, wbuf_o, 2097152L);
    // 5-6. RoPE + V transpose (fold qkv partial-sum)
    rope_kernel<<<dim3(40, 2048), 128, 0, stream>>>(positions, qkvp0, qkvp1, qb, kb);
    vtrans_kernel<<<dim3(32, 8), 256, 0, stream>>>(qkvp0, qkvp1, vt);
    // 7. flash attention
    flash_kernel<<<dim3(32, 32), 256, 0, stream>>>(qb, kb, vt, ctx);
    // 8. o-proj (2-way K-split partials)
    gemm8<0,2><<<dim3(16, 8, 2), 512, 0, stream>>>(ctx, wbuf_o, Po, nullptr, 4096, 4096);
    // 9. residual2 = Po0+Po1+residual1 ; h2 = rmsnorm(residual2)
    add_rmsnorm_kernel<<<2048, 256, 0, stream>>>(Po, Po + 8388608, resid1, w_ln2, resid2, h2);
    // 10. gate_up GEMM + fused silu -> hm bf16 [2048][14336]
    gemm8<3,1><<<dim3(112, 8, 1), 512, 0, stream>>>(h2, wbuf, nullptr, hm, 14336, 4096);
    // 11. down (2-way K-split partials) ; out = Pd0+Pd1
    wconv_kernel<<<2048, 256, 0, stream>>>(w_down, wbuf, 7340032L);
    gemm8<0,2><<<dim3(16, 8, 2), 512, 0, stream>>>(hm, wbuf, Pd, nullptr, 4096, 14336);
    add2_kernel<<<2048, 256, 0, stream>>>(Pd, Pd + 8388608, out_f, 2097152L);
}

// Round 11
// 1396.377 us; speedup vs baseline: 1.0686x; 1.0686x over previous
//
#include <hip/hip_runtime.h>

typedef short bf16x8 __attribute__((ext_vector_type(8)));
typedef short short4v __attribute__((ext_vector_type(4)));
typedef float f32x4 __attribute__((ext_vector_type(4)));

#define SCALE_ATTN 0.08838834764831845f

__device__ inline short f2bs(float f) {
    unsigned u = __builtin_bit_cast(unsigned, f);
    unsigned r = (u + 0x7fffu + ((u >> 16) & 1u)) >> 16;
    return (short)(unsigned short)r;
}
__device__ inline float b2f(short s) {
    unsigned u = ((unsigned)(unsigned short)s) << 16;
    return __builtin_bit_cast(float, u);
}
__device__ inline void pack_w4(const f32x4& a, const f32x4& b, bf16x8& p) {
    p[0] = f2bs(a[0]); p[1] = f2bs(a[1]); p[2] = f2bs(a[2]); p[3] = f2bs(a[3]);
    p[4] = f2bs(b[0]); p[5] = f2bs(b[1]); p[6] = f2bs(b[2]); p[7] = f2bs(b[3]);
}

// ---------------------------------------------------------------------------
// weight convert f32 -> bf16 (RNE), grid-stride, NT both ways (R8-proven).
// ---------------------------------------------------------------------------
__global__ __launch_bounds__(256)
void wconv_kernel(const float* __restrict__ src, short* __restrict__ dst, long n8)
{
    const long stride = (long)gridDim.x << 8;
    for (long i = ((long)blockIdx.x << 8) + threadIdx.x; i < n8; i += stride) {
        const f32x4 a = __builtin_nontemporal_load(&((const f32x4*)src)[i << 1]);
        const f32x4 b = __builtin_nontemporal_load(&((const f32x4*)src)[(i << 1) + 1]);
        bf16x8 p;
        pack_w4(a, b, p);
        __builtin_nontemporal_store(p, &((bf16x8*)dst)[i]);
    }
}

// ---------------------------------------------------------------------------
// fused (X [+X2] [+Rin]) -> Rout(f32), rmsnorm -> Hout(bf16). 1 block/row.
// ---------------------------------------------------------------------------
__global__ __launch_bounds__(256)
void add_rmsnorm_kernel(const float* __restrict__ X, const float* __restrict__ X2,
                        const float* __restrict__ Rin, const float* __restrict__ w,
                        float* __restrict__ Rout, short* __restrict__ Hout)
{
    const int tid = threadIdx.x;
    const long base = (long)blockIdx.x << 12;
    float v[16];
    float ss = 0.f;
#pragma unroll
    for (int p = 0; p < 4; ++p) {
        const int idx = (p << 10) + (tid << 2);
        f32x4 a = *(const f32x4*)(X + base + idx);
        if (X2 != nullptr) {
            f32x4 b = *(const f32x4*)(X2 + base + idx);
            a += b;
        }
        if (Rin != nullptr) {
            f32x4 b = *(const f32x4*)(Rin + base + idx);
            a += b;
        }
        v[p*4+0] = a[0]; v[p*4+1] = a[1]; v[p*4+2] = a[2]; v[p*4+3] = a[3];
        ss += a[0]*a[0] + a[1]*a[1] + a[2]*a[2] + a[3]*a[3];
    }
#pragma unroll
    for (int dd = 1; dd < 64; dd <<= 1) ss += __shfl_xor(ss, dd);
    __shared__ float red[4];
    if ((tid & 63) == 0) red[tid >> 6] = ss;
    __syncthreads();
    const float tot = red[0] + red[1] + red[2] + red[3];
    const float rstd = rsqrtf(tot * (1.0f / 4096.0f) + 1e-5f);
#pragma unroll
    for (int p = 0; p < 4; ++p) {
        const int idx = (p << 10) + (tid << 2);
        if (Rout != nullptr) {
            f32x4 b;
            b[0] = v[p*4+0]; b[1] = v[p*4+1]; b[2] = v[p*4+2]; b[3] = v[p*4+3];
            *(f32x4*)(Rout + base + idx) = b;
        }
        f32x4 wv4 = *(const f32x4*)(w + idx);
        short4v hb;
        hb[0] = f2bs(v[p*4+0] * rstd * wv4[0]);
        hb[1] = f2bs(v[p*4+1] * rstd * wv4[1]);
        hb[2] = f2bs(v[p*4+2] * rstd * wv4[2]);
        hb[3] = f2bs(v[p*4+3] * rstd * wv4[3]);
        *(short4v*)(Hout + base + idx) = hb;
    }
}

// ---------------------------------------------------------------------------
// out = a + b (f32)
// ---------------------------------------------------------------------------
__global__ __launch_bounds__(256)
void add2_kernel(const float* __restrict__ a, const float* __restrict__ b,
                 float* __restrict__ o, long n4)
{
    const long st = (long)gridDim.x << 8;
    for (long i = ((long)blockIdx.x << 8) + threadIdx.x; i < n4; i += st) {
        f32x4 x = __builtin_nontemporal_load(&((const f32x4*)a)[i]);
        f32x4 y = __builtin_nontemporal_load(&((const f32x4*)b)[i]);
        x += y;
        ((f32x4*)o)[i] = x;
    }
}

// ---------------------------------------------------------------------------
// SiLU(gate)*up : gu bf16 [S, 28672] -> hm bf16 [S, 14336].  NT loads (gu is
// single-use; don't evict hm/weight slab from L3).
// ---------------------------------------------------------------------------
__global__ __launch_bounds__(256)
void silu_kernel(const short* __restrict__ gu, short* __restrict__ hm)
{
    const int s = blockIdx.y;
    const int j = ((blockIdx.x << 8) + threadIdx.x) << 3;
    const short* g = gu + (long)s * 28672 + j;
    bf16x8 gv = __builtin_nontemporal_load((const bf16x8*)g);
    bf16x8 uv = __builtin_nontemporal_load((const bf16x8*)(g + 14336));
    bf16x8 ov;
#pragma unroll
    for (int e = 0; e < 8; ++e) {
        const float gf = b2f(gv[e]);
        const float uf = b2f(uv[e]);
        const float r = gf / (1.f + __expf(-gf)) * uf;
        ov[e] = f2bs(r);
    }
    *(bf16x8*)(hm + (long)s * 14336 + j) = ov;
}

// ===========================================================================
// 8-phase 256x256 GEMM (R3/R8-proven body), XCD swizzle, optional 2-way
// K-split.  EPI 0: f32 store (+KS partial offset).  EPI 2: bf16 store.
// EPI3 (fused silu) PERMANENTLY REVERTED: R5/R7/R9/R10 all show +401 MiB
// WRITE / +115 MiB FETCH / +130 us regardless of store policy or placement.
// ===========================================================================
#define BAR()   do { asm volatile("" ::: "memory"); __builtin_amdgcn_s_barrier(); asm volatile("" ::: "memory"); } while (0)
#define LGKM0() asm volatile("s_waitcnt lgkmcnt(0)" ::: "memory")
#define VMW(n)  asm volatile("s_waitcnt vmcnt(" #n ")" ::: "memory")

__device__ inline bf16x8 lds_frag(const short* tile, int row, int kb) {
    const int off = row * 128 + (kb ^ ((row & 7) << 4));
    return *(const bf16x8*)((const char*)tile + off);
}

// stage one half-tile (128 rows x 64 k): linear LDS dest, inverse-swizzled src
__device__ inline void stage_half(const short* __restrict__ G, long grow0, long K,
                                  long k0, short* ldsHalf, int wv, int lane)
{
#pragma unroll
    for (int i = 0; i < 2; ++i) {
        short* dst = ldsHalf + ((i << 13) + (wv << 10)) / 2;   // wave-uniform
        const int off = (wv << 10) + (i << 13) + (lane << 4);  // lane's byte slot
        const int r   = off >> 7;
        const int cb  = off & 127;
        const int gcb = cb ^ ((r & 7) << 4);
        const short* src = G + (grow0 + r) * K + k0 + (gcb >> 1);
        __builtin_amdgcn_global_load_lds(
            (const __attribute__((address_space(1))) void*)(const void*)src,
            (__attribute__((address_space(3))) void*)(void*)dst, 16, 0, 0);
    }
}

#define LOAD_A(T, grp) do {                                        \
    _Pragma("unroll") for (int _m = 0; _m < 4; ++_m) {             \
        const int _row = abase + (grp)*64 + _m*16 + l15;           \
        a[_m][0] = lds_frag(T, _row, l4b);                         \
        a[_m][1] = lds_frag(T, _row, 64 + l4b);                    \
    } } while (0)

#define LOAD_B(T, n0) do {                                         \
    _Pragma("unroll") for (int _n = 0; _n < 2; ++_n) {             \
        const int _row = bbase + ((n0)+_n)*16 + l15;               \
        b[(n0)+_n][0] = lds_frag(T, _row, l4b);                    \
        b[(n0)+_n][1] = lds_frag(T, _row, 64 + l4b);               \
    } } while (0)

#define MFMA16(MB, NB) do {                                                        \
    __builtin_amdgcn_s_setprio(1);                                                 \
    _Pragma("unroll") for (int _m = 0; _m < 4; ++_m)                               \
    _Pragma("unroll") for (int _n = 0; _n < 2; ++_n) {                             \
        acc[(MB)+_m][(NB)+_n] = __builtin_amdgcn_mfma_f32_16x16x32_bf16(           \
            a[_m][0], b[(NB)+_n][0], acc[(MB)+_m][(NB)+_n], 0, 0, 0);              \
        acc[(MB)+_m][(NB)+_n] = __builtin_amdgcn_mfma_f32_16x16x32_bf16(           \
            a[_m][1], b[(NB)+_n][1], acc[(MB)+_m][(NB)+_n], 0, 0, 0);              \
    }                                                                              \
    __builtin_amdgcn_s_setprio(0);                                                 \
} while (0)

template<int EPI, int KS>
__global__ __launch_bounds__(512, 2)
void gemm8(const short* __restrict__ A, const short* __restrict__ W,
           float* __restrict__ Cf, short* __restrict__ Cb,
           int N, int K)
{
    __shared__ __align__(16) short As[2][16384];
    __shared__ __align__(16) short Bs[2][16384];

    const int tid  = threadIdx.x;
    const int lane = tid & 63;
    const int wv   = tid >> 6;
    const int wm   = wv >> 2;
    const int wn   = wv & 3;
    const int l15  = lane & 15;
    const int l4b  = (lane >> 4) << 4;

    // XCD swizzle; within an XCD: 8 consecutive blocks share one (bx,kz) panel
    const int gx   = gridDim.x;
    const int nwg  = gx * 8 * KS;
    const int cpx  = nwg >> 3;
    const int orig = (blockIdx.z * 8 + blockIdx.y) * gx + blockIdx.x;
    const int lgc  = (orig & 7) * cpx + (orig >> 3);
    const int by   = lgc & 7;
    const int tq   = lgc >> 3;
    const int kz   = (KS == 1) ? 0 : (tq % KS);
    const int bx   = (KS == 1) ? tq : (tq / KS);

    const long row0 = (long)by << 8;
    const long col0 = (long)bx << 8;
    const int abase = wm << 7;
    const int bbase = wn << 6;

    const int  Kc    = K / KS;
    const long kbase = (long)kz * Kc;
    const int  iters = Kc >> 7;

    f32x4 acc[8][4];
#pragma unroll
    for (int i = 0; i < 8; ++i)
#pragma unroll
        for (int j = 0; j < 4; ++j) acc[i][j] = (f32x4){0.f,0.f,0.f,0.f};

    bf16x8 a[4][2], b[4][2];

    // prologue: stage buf0 (tile0) then buf1 (tile1)
    stage_half(A, row0,       K, kbase,      &As[0][0],    wv, lane);
    stage_half(A, row0 + 128, K, kbase,      &As[0][8192], wv, lane);
    stage_half(W, col0,       K, kbase,      &Bs[0][0],    wv, lane);
    stage_half(W, col0 + 128, K, kbase,      &Bs[0][8192], wv, lane);
    stage_half(A, row0,       K, kbase + 64, &As[1][0],    wv, lane);
    stage_half(A, row0 + 128, K, kbase + 64, &As[1][8192], wv, lane);
    stage_half(W, col0,       K, kbase + 64, &Bs[1][0],    wv, lane);
    stage_half(W, col0 + 128, K, kbase + 64, &Bs[1][8192], wv, lane);
    VMW(8);
    BAR();

#pragma unroll 1
    for (int it = 0; it < iters; ++it) {
        const long k2 = kbase + ((long)(2*it + 2) << 6);
        const long k3 = k2 + 64;
        const bool pf = (it + 1 < iters);

        // ---------------- tile 2it (buf0) ----------------
        // P1
        LOAD_A(As[0], 0); LOAD_B(Bs[0], 0);
        BAR(); LGKM0(); MFMA16(0, 0); BAR();
        // P2
        LOAD_B(Bs[0], 2);
        BAR(); LGKM0(); MFMA16(0, 2); BAR();
        // P3
        LOAD_A(As[0], 1);
        if (pf) stage_half(W, col0, K, k2, &Bs[0][0], wv, lane);
        BAR(); LGKM0(); MFMA16(4, 0); BAR();
        // P4
        if (pf) {
            stage_half(A, row0,       K, k2, &As[0][0],    wv, lane);
            stage_half(W, col0 + 128, K, k2, &Bs[0][8192], wv, lane);
        }
        VMW(6);
        BAR(); MFMA16(4, 2); BAR();

        // ---------------- tile 2it+1 (buf1) ----------------
        // P5
        LOAD_A(As[1], 0); LOAD_B(Bs[1], 0);
        if (pf) stage_half(A, row0 + 128, K, k2, &As[0][8192], wv, lane);
        BAR(); LGKM0(); MFMA16(0, 0); BAR();
        // P6
        LOAD_B(Bs[1], 2);
        BAR(); LGKM0(); MFMA16(0, 2); BAR();
        // P7
        LOAD_A(As[1], 1);
        if (pf) {
            stage_half(W, col0,       K, k3, &Bs[1][0],    wv, lane);
            stage_half(W, col0 + 128, K, k3, &Bs[1][8192], wv, lane);
        }
        BAR(); LGKM0(); MFMA16(4, 0); BAR();
        // P8
        if (pf) {
            stage_half(A, row0,       K, k3, &As[1][0],    wv, lane);
            stage_half(A, row0 + 128, K, k3, &As[1][8192], wv, lane);
        }
        VMW(8);
        BAR(); MFMA16(4, 2); BAR();
    }

    if (EPI == 0) {
        float* Cfp = Cf + ((KS > 1) ? (long)kz * ((long)N << 11) : 0);
#pragma unroll
        for (int m = 0; m < 8; ++m) {
#pragma unroll
            for (int n = 0; n < 4; ++n) {
                const long gr = row0 + (wm << 7) + m*16 + ((lane >> 4) << 2);
                const long gc = col0 + (wn << 6) + n*16 + l15;
#pragma unroll
                for (int r = 0; r < 4; ++r)
                    Cfp[(gr + r) * N + gc] = acc[m][n][r];
            }
        }
    } else {
#pragma unroll
        for (int m = 0; m < 8; ++m) {
#pragma unroll
            for (int n = 0; n < 4; ++n) {
                const long gr = row0 + (wm << 7) + m*16 + ((lane >> 4) << 2);
                const long gc = col0 + (wn << 6) + n*16 + l15;
#pragma unroll
                for (int r = 0; r < 4; ++r)
                    Cb[(gr + r) * N + gc] = f2bs(acc[m][n][r]);
            }
        }
    }
}

// ---------------------------------------------------------------------------
// RoPE (reads 2 K-split partials of qkv f32 and sums)
// ---------------------------------------------------------------------------
__global__ __launch_bounds__(128)
void rope_kernel(const int* __restrict__ pos, const float* __restrict__ q0p,
                 const float* __restrict__ q1p,
                 short* __restrict__ Qo, short* __restrict__ Ko)
{
    const int h = blockIdx.x;
    const int s = blockIdx.y;
    const int d = threadIdx.x;
    const int j = d & 63;
    const float p = (float)pos[s];
    const float invf = __expf((float)j * -0.20503692895f);  // ln(5e5)/64
    float sn, cs;
    __sincosf(p * invf, &sn, &cs);
    const long base = (long)s * 6144 + h * 128;
    const float x1 = q0p[base + j] + q1p[base + j];
    const float x2 = q0p[base + 64 + j] + q1p[base + 64 + j];
    const float outv = (d < 64) ? (x1 * cs - x2 * sn) : (x2 * cs + x1 * sn);
    const short ob = f2bs(outv);
    if (h < 32) Qo[(long)s * 4096 + h * 128 + d] = ob;
    else        Ko[(long)s * 1024 + (h - 32) * 128 + d] = ob;
}

// ---------------------------------------------------------------------------
// V transpose: qkv partials f32 v-part [S,8,128] -> Vt bf16 [8][128][S]
// ---------------------------------------------------------------------------
__global__ __launch_bounds__(256)
void vtrans_kernel(const float* __restrict__ q0p, const float* __restrict__ q1p,
                   short* __restrict__ Vt)
{
    __shared__ short tile[64][136];
    const int tid = threadIdx.x;
    const int s0 = blockIdx.x << 6;
    const int h = blockIdx.y;
    {
        const int srow = tid >> 2;
        const int c0 = (tid & 3) << 5;
        const long off = (long)(s0 + srow) * 6144 + 5120 + h * 128 + c0;
#pragma unroll
        for (int m = 0; m < 8; ++m) {
            f32x4 f = *(const f32x4*)(q0p + off + (m << 2));
            f32x4 g = *(const f32x4*)(q1p + off + (m << 2));
            f += g;
            tile[srow][c0 + (m << 2) + 0] = f2bs(f[0]);
            tile[srow][c0 + (m << 2) + 1] = f2bs(f[1]);
            tile[srow][c0 + (m << 2) + 2] = f2bs(f[2]);
            tile[srow][c0 + (m << 2) + 3] = f2bs(f[3]);
        }
    }
    __syncthreads();
    {
        const int d = tid >> 1;
        const int sc = (tid & 1) << 5;
        short* dst = Vt + ((long)h * 128 + d) * 2048 + s0 + sc;
#pragma unroll
        for (int m = 0; m < 4; ++m) {
            bf16x8 v;
#pragma unroll
            for (int e = 0; e < 8; ++e) v[e] = tile[sc + (m << 3) + e][d];
            *(bf16x8*)(dst + (m << 3)) = v;
        }
    }
}

// ---------------------------------------------------------------------------
// Flash attention (causal, GQA rep=4)
// ---------------------------------------------------------------------------
__global__ __launch_bounds__(256)
void flash_kernel(const short* __restrict__ Qg, const short* __restrict__ Kg,
                  const short* __restrict__ Vtg, short* __restrict__ Ctx)
{
    __shared__ short Qs[64 * 128];
    __shared__ short Ks[64 * 128];
    __shared__ short Vs[128 * 64];
    __shared__ short Ps[4 * 16 * 64];

    const int tid  = threadIdx.x;
    const int lane = tid & 63;
    const int wv   = tid >> 6;
    const int l15  = lane & 15;
    const int l4e  = (lane >> 4) << 3;
    const int qt   = blockIdx.x;
    const int head = blockIdx.y;
    const int q0   = qt << 6;
    const int kvh  = head >> 2;

    {   // stage Q (swizzled)
        const int row = tid >> 2;
        const int c0 = (tid & 3) << 5;
        const short* src = Qg + (long)(q0 + row) * 4096 + head * 128 + c0;
        const int sw = (row & 7) << 3;
#pragma unroll
        for (int m = 0; m < 4; ++m) {
            bf16x8 v = *(const bf16x8*)(src + (m << 3));
            *(bf16x8*)&Qs[row * 128 + ((c0 + (m << 3)) ^ sw)] = v;
        }
    }

    float mrow[4], lrow[4];
    f32x4 o[8];
#pragma unroll
    for (int r = 0; r < 4; ++r) { mrow[r] = -__builtin_inff(); lrow[r] = 0.f; }
#pragma unroll
    for (int d = 0; d < 8; ++d) o[d] = (f32x4){0.f,0.f,0.f,0.f};

    for (int t = 0; t <= qt; ++t) {
        const int kv0 = t << 6;
        __syncthreads();
        {   // stage K
            const int row = tid >> 2;
            const int c0 = (tid & 3) << 5;
            const short* src = Kg + (long)(kv0 + row) * 1024 + kvh * 128 + c0;
            const int sw = (row & 7) << 3;
#pragma unroll
            for (int m = 0; m < 4; ++m) {
                bf16x8 v = *(const bf16x8*)(src + (m << 3));
                *(bf16x8*)&Ks[row * 128 + ((c0 + (m << 3)) ^ sw)] = v;
            }
        }
        {   // stage Vt
            const int d = tid >> 1;
            const int c0 = (tid & 1) << 5;
            const short* src = Vtg + ((long)kvh * 128 + d) * 2048 + kv0 + c0;
            const int sw = (d & 7) << 3;
#pragma unroll
            for (int m = 0; m < 4; ++m) {
                bf16x8 v = *(const bf16x8*)(src + (m << 3));
                *(bf16x8*)&Vs[d * 64 + ((c0 + (m << 3)) ^ sw)] = v;
            }
        }
        __syncthreads();

        bf16x8 qa[4];
        {
            const int qrow = (wv << 4) + l15;
            const int sw = (qrow & 7) << 3;
#pragma unroll
            for (int kk = 0; kk < 4; ++kk)
                qa[kk] = *(const bf16x8*)&Qs[qrow * 128 + ((l4e + (kk << 5)) ^ sw)];
        }
        f32x4 sacc[4];
#pragma unroll
        for (int j = 0; j < 4; ++j) {
            sacc[j] = (f32x4){0.f,0.f,0.f,0.f};
            const int krow = (j << 4) + l15;
            const int sw = (krow & 7) << 3;
#pragma unroll
            for (int kk = 0; kk < 4; ++kk) {
                bf16x8 kb8 = *(const bf16x8*)&Ks[krow * 128 + ((l4e + (kk << 5)) ^ sw)];
                sacc[j] = __builtin_amdgcn_mfma_f32_16x16x32_bf16(qa[kk], kb8, sacc[j], 0, 0, 0);
            }
        }

#pragma unroll
        for (int ri = 0; ri < 4; ++ri) {
            const int grow = q0 + (wv << 4) + ((lane >> 4) << 2) + ri;
            float sv[4];
#pragma unroll
            for (int j = 0; j < 4; ++j) {
                float s = sacc[j][ri] * SCALE_ATTN;
                const int col = kv0 + (j << 4) + l15;
                sv[j] = (col > grow) ? -1e30f : s;
            }
            float mx = fmaxf(fmaxf(sv[0], sv[1]), fmaxf(sv[2], sv[3]));
#pragma unroll
            for (int dd = 1; dd < 16; dd <<= 1) mx = fmaxf(mx, __shfl_xor(mx, dd));
            const float mnew = fmaxf(mrow[ri], mx);
            const float alpha = __expf(mrow[ri] - mnew);
            mrow[ri] = mnew;
            float psum = 0.f;
            short pb[4];
#pragma unroll
            for (int j = 0; j < 4; ++j) {
                float p = __expf(sv[j] - mnew);
                psum += p;
                pb[j] = f2bs(p);
            }
            lrow[ri] = lrow[ri] * alpha + psum;
#pragma unroll
            for (int d = 0; d < 8; ++d) o[d][ri] *= alpha;
            const int prow = ((lane >> 4) << 2) + ri;
            const int sw = (prow & 7) << 3;
#pragma unroll
            for (int j = 0; j < 4; ++j)
                Ps[(wv << 10) + prow * 64 + ((((j << 4) + l15)) ^ sw)] = pb[j];
        }

        bf16x8 pa0, pa1;
        {
            const int prow = l15;
            const int sw = (prow & 7) << 3;
            pa0 = *(const bf16x8*)&Ps[(wv << 10) + prow * 64 + (l4e ^ sw)];
            pa1 = *(const bf16x8*)&Ps[(wv << 10) + prow * 64 + ((l4e + 32) ^ sw)];
        }
#pragma unroll
        for (int fd = 0; fd < 8; ++fd) {
            const int drow = (fd << 4) + l15;
            const int sw = (drow & 7) << 3;
            bf16x8 v0 = *(const bf16x8*)&Vs[drow * 64 + (l4e ^ sw)];
            bf16x8 v1 = *(const bf16x8*)&Vs[drow * 64 + ((l4e + 32) ^ sw)];
            o[fd] = __builtin_amdgcn_mfma_f32_16x16x32_bf16(pa0, v0, o[fd], 0, 0, 0);
            o[fd] = __builtin_amdgcn_mfma_f32_16x16x32_bf16(pa1, v1, o[fd], 0, 0, 0);
        }
    }

    float inv[4];
#pragma unroll
    for (int ri = 0; ri < 4; ++ri) {
        float ls = lrow[ri];
#pragma unroll
        for (int dd = 1; dd < 16; dd <<= 1) ls += __shfl_xor(ls, dd);
        inv[ri] = 1.0f / ls;
    }
#pragma unroll
    for (int fd = 0; fd < 8; ++fd)
#pragma unroll
        for (int ri = 0; ri < 4; ++ri) {
            const long row = q0 + (wv << 4) + ((lane >> 4) << 2) + ri;
            Ctx[row * 4096 + head * 128 + (fd << 4) + l15] = f2bs(o[fd][ri] * inv[ri]);
        }
}

// ---------------------------------------------------------------------------
extern "C" void kernel_launch(void* const* d_in, const int* in_sizes, int n_in,
                              void* d_out, int out_size, void* d_ws, size_t ws_size,
                              hipStream_t stream)
{
    const int*   positions = (const int*)d_in[0];
    const float* hidden    = (const float*)d_in[1];
    const float* residual  = (const float*)d_in[2];
    const float* w_qkv     = (const float*)d_in[3];
    const float* w_o       = (const float*)d_in[4];
    const float* w_gu      = (const float*)d_in[5];
    const float* w_down    = (const float*)d_in[6];
    const float* w_ln1     = (const float*)d_in[7];
    const float* w_ln2     = (const float*)d_in[8];

    float* out_f   = (float*)d_out;              // [2048,4096] final output
    float* resid2  = out_f + 8388608;            // [2048,4096] residual output
    float* resid1  = out_f;                      // scratch: dead before add2 writes

    char* wsb = (char*)d_ws;
    short* h1     = (short*)(wsb + 0);           // 16 MiB (dead after qkv gemm)
    short* ctx    = (short*)(wsb + 0);           // reuse (dead after o gemm)
    float* qkvp0  = (float*)(wsb + 16777216);    // 48 MiB partial 0 (16..64, dead after rope/vtrans)
    float* qkvp1  = (float*)(wsb + 67108864);    // 48 MiB partial 1 (64..112, dead after rope/vtrans)
    short* h2     = (short*)(wsb + 16777216);    // reuse (16..32, dead after gate_up)
    float* Po     = (float*)(wsb + 33554432);    // 2x32 MiB o partials (32..96, dead after rms2)
    short* qb     = (short*)(wsb + 117440512);   // 16 MiB (112..128, dead after flash)
    short* kb     = (short*)(wsb + 134217728);   //  4 MiB (128..132, dead after flash)
    short* vt     = (short*)(wsb + 138412032);   //  4 MiB (132..136, dead after flash)
    short* gu     = (short*)(wsb + 33554432);    // 112 MiB (32..144, over dead Po/qkvp/qb/kb/vt)
    short* hm     = (short*)(wsb + 150994944);   // 56 MiB (144..200)
    float* Pd     = (float*)(wsb + 0);           // 2x32 MiB down partials (0..64; ctx/h2/gu-head dead)
    short* wbuf   = (short*)(wsb + 209715200);   // 224 MiB bf16 weight slab (200..424)
    short* wbuf_o = wbuf + 25165824;             // o weights at slab+48 MiB (coexist w/ qkv weights)

    // 1. residual1 = hidden + residual ; h1 = rmsnorm(residual1)
    add_rmsnorm_kernel<<<2048, 256, 0, stream>>>(hidden, nullptr, residual, w_ln1, resid1, h1);
    // 2. qkv (2-way K-split partials; summed inside rope/vtrans)
    wconv_kernel<<<2048, 256, 0, stream>>>(w_qkv, wbuf, 3145728L);
    gemm8<0,2><<<dim3(24, 8, 2), 512, 0, stream>>>(h1, wbuf, qkvp0, nullptr, 6144, 4096);
    // 3. o weights early (writeback settles during rope/vtrans/flash)
    wconv_kernel<<<2048, 256, 0, stream>>>(w_o, wbuf_o, 2097152L);
    // 4-5. RoPE + V transpose (fold qkv partial-sum)
    rope_kernel<<<dim3(40, 2048), 128, 0, stream>>>(positions, qkvp0, qkvp1, qb, kb);
    vtrans_kernel<<<dim3(32, 8), 256, 0, stream>>>(qkvp0, qkvp1, vt);
    // 6. flash attention
    flash_kernel<<<dim3(32, 32), 256, 0, stream>>>(qb, kb, vt, ctx);
    // 7. o-proj (2-way K-split partials)
    gemm8<0,2><<<dim3(16, 8, 2), 512, 0, stream>>>(ctx, wbuf_o, Po, nullptr, 4096, 4096);
    // 8. residual2 = Po0+Po1+residual1 ; h2 = rmsnorm(residual2)
    add_rmsnorm_kernel<<<2048, 256, 0, stream>>>(Po, Po + 8388608, resid1, w_ln2, resid2, h2);
    // 9. gate_up -> gu bf16 [2048][28672]  (EPI2, R8-proven)
    wconv_kernel<<<2048, 256, 0, stream>>>(w_gu, wbuf, 14680064L);
    gemm8<2,1><<<dim3(112, 8, 1), 512, 0, stream>>>(h2, wbuf, nullptr, gu, 28672, 4096);
    // 10. hm = silu(gate)*up
    silu_kernel<<<dim3(7, 2048), 256, 0, stream>>>(gu, hm);
    // 11. down (2-way K-split partials) ; out = Pd0+Pd1
    wconv_kernel<<<2048, 256, 0, stream>>>(w_down, wbuf, 7340032L);
    gemm8<0,2><<<dim3(16, 8, 2), 512, 0, stream>>>(hm, wbuf, Pd, nullptr, 4096, 14336);
    add2_kernel<<<2048, 256, 0, stream>>>(Pd, Pd + 8388608, out_f, 2097152L);
}

// Round 12
// 1308.624 us; speedup vs baseline: 1.1403x; 1.0671x over previous
//
#include <hip/hip_runtime.h>

typedef short bf16x8 __attribute__((ext_vector_type(8)));
typedef short short4v __attribute__((ext_vector_type(4)));
typedef float f32x4 __attribute__((ext_vector_type(4)));

#define SCALE_ATTN 0.08838834764831845f

__device__ inline short f2bs(float f) {
    unsigned u = __builtin_bit_cast(unsigned, f);
    unsigned r = (u + 0x7fffu + ((u >> 16) & 1u)) >> 16;
    return (short)(unsigned short)r;
}
__device__ inline float b2f(short s) {
    unsigned u = ((unsigned)(unsigned short)s) << 16;
    return __builtin_bit_cast(float, u);
}
__device__ inline void pack_w4(const f32x4& a, const f32x4& b, bf16x8& p) {
    p[0] = f2bs(a[0]); p[1] = f2bs(a[1]); p[2] = f2bs(a[2]); p[3] = f2bs(a[3]);
    p[4] = f2bs(b[0]); p[5] = f2bs(b[1]); p[6] = f2bs(b[2]); p[7] = f2bs(b[3]);
}

// ---------------------------------------------------------------------------
// weight convert f32 -> bf16 (RNE), grid-stride, NT both ways (R8-proven).
// ---------------------------------------------------------------------------
__global__ __launch_bounds__(256)
void wconv_kernel(const float* __restrict__ src, short* __restrict__ dst, long n8)
{
    const long stride = (long)gridDim.x << 8;
    for (long i = ((long)blockIdx.x << 8) + threadIdx.x; i < n8; i += stride) {
        const f32x4 a = __builtin_nontemporal_load(&((const f32x4*)src)[i << 1]);
        const f32x4 b = __builtin_nontemporal_load(&((const f32x4*)src)[(i << 1) + 1]);
        bf16x8 p;
        pack_w4(a, b, p);
        __builtin_nontemporal_store(p, &((bf16x8*)dst)[i]);
    }
}

// ---------------------------------------------------------------------------
// fused (X [+X2] [+Rin]) -> Rout(f32), rmsnorm -> Hout(bf16). 1 block/row.
// ---------------------------------------------------------------------------
__global__ __launch_bounds__(256)
void add_rmsnorm_kernel(const float* __restrict__ X, const float* __restrict__ X2,
                        const float* __restrict__ Rin, const float* __restrict__ w,
                        float* __restrict__ Rout, short* __restrict__ Hout)
{
    const int tid = threadIdx.x;
    const long base = (long)blockIdx.x << 12;
    float v[16];
    float ss = 0.f;
#pragma unroll
    for (int p = 0; p < 4; ++p) {
        const int idx = (p << 10) + (tid << 2);
        f32x4 a = *(const f32x4*)(X + base + idx);
        if (X2 != nullptr) {
            f32x4 b = *(const f32x4*)(X2 + base + idx);
            a += b;
        }
        if (Rin != nullptr) {
            f32x4 b = *(const f32x4*)(Rin + base + idx);
            a += b;
        }
        v[p*4+0] = a[0]; v[p*4+1] = a[1]; v[p*4+2] = a[2]; v[p*4+3] = a[3];
        ss += a[0]*a[0] + a[1]*a[1] + a[2]*a[2] + a[3]*a[3];
    }
#pragma unroll
    for (int dd = 1; dd < 64; dd <<= 1) ss += __shfl_xor(ss, dd);
    __shared__ float red[4];
    if ((tid & 63) == 0) red[tid >> 6] = ss;
    __syncthreads();
    const float tot = red[0] + red[1] + red[2] + red[3];
    const float rstd = rsqrtf(tot * (1.0f / 4096.0f) + 1e-5f);
#pragma unroll
    for (int p = 0; p < 4; ++p) {
        const int idx = (p << 10) + (tid << 2);
        if (Rout != nullptr) {
            f32x4 b;
            b[0] = v[p*4+0]; b[1] = v[p*4+1]; b[2] = v[p*4+2]; b[3] = v[p*4+3];
            *(f32x4*)(Rout + base + idx) = b;
        }
        f32x4 wv4 = *(const f32x4*)(w + idx);
        short4v hb;
        hb[0] = f2bs(v[p*4+0] * rstd * wv4[0]);
        hb[1] = f2bs(v[p*4+1] * rstd * wv4[1]);
        hb[2] = f2bs(v[p*4+2] * rstd * wv4[2]);
        hb[3] = f2bs(v[p*4+3] * rstd * wv4[3]);
        *(short4v*)(Hout + base + idx) = hb;
    }
}

// ---------------------------------------------------------------------------
// out = a + b (f32)
// ---------------------------------------------------------------------------
__global__ __launch_bounds__(256)
void add2_kernel(const float* __restrict__ a, const float* __restrict__ b,
                 float* __restrict__ o, long n4)
{
    const long st = (long)gridDim.x << 8;
    for (long i = ((long)blockIdx.x << 8) + threadIdx.x; i < n4; i += st) {
        f32x4 x = __builtin_nontemporal_load(&((const f32x4*)a)[i]);
        f32x4 y = __builtin_nontemporal_load(&((const f32x4*)b)[i]);
        x += y;
        ((f32x4*)o)[i] = x;
    }
}

// ---------------------------------------------------------------------------
// SiLU(gate)*up : gu bf16 [S, 28672] -> hm bf16 [S, 14336].  NT loads.
// ---------------------------------------------------------------------------
__global__ __launch_bounds__(256)
void silu_kernel(const short* __restrict__ gu, short* __restrict__ hm)
{
    const int s = blockIdx.y;
    const int j = ((blockIdx.x << 8) + threadIdx.x) << 3;
    const short* g = gu + (long)s * 28672 + j;
    bf16x8 gv = __builtin_nontemporal_load((const bf16x8*)g);
    bf16x8 uv = __builtin_nontemporal_load((const bf16x8*)(g + 14336));
    bf16x8 ov;
#pragma unroll
    for (int e = 0; e < 8; ++e) {
        const float gf = b2f(gv[e]);
        const float uf = b2f(uv[e]);
        const float r = gf / (1.f + __expf(-gf)) * uf;
        ov[e] = f2bs(r);
    }
    *(bf16x8*)(hm + (long)s * 14336 + j) = ov;
}

// ===========================================================================
// 8-phase 256x256 GEMM (R3/R8-proven body), XCD swizzle, optional 2-way
// K-split.  EPI 0: f32 store (+KS partial offset).  EPI 2: bf16 store.
// ===========================================================================
#define BAR()   do { asm volatile("" ::: "memory"); __builtin_amdgcn_s_barrier(); asm volatile("" ::: "memory"); } while (0)
#define LGKM0() asm volatile("s_waitcnt lgkmcnt(0)" ::: "memory")
#define VMW(n)  asm volatile("s_waitcnt vmcnt(" #n ")" ::: "memory")

__device__ inline bf16x8 lds_frag(const short* tile, int row, int kb) {
    const int off = row * 128 + (kb ^ ((row & 7) << 4));
    return *(const bf16x8*)((const char*)tile + off);
}

// stage one half-tile (128 rows x 64 k): linear LDS dest, inverse-swizzled src
__device__ inline void stage_half(const short* __restrict__ G, long grow0, long K,
                                  long k0, short* ldsHalf, int wv, int lane)
{
#pragma unroll
    for (int i = 0; i < 2; ++i) {
        short* dst = ldsHalf + ((i << 13) + (wv << 10)) / 2;   // wave-uniform
        const int off = (wv << 10) + (i << 13) + (lane << 4);  // lane's byte slot
        const int r   = off >> 7;
        const int cb  = off & 127;
        const int gcb = cb ^ ((r & 7) << 4);
        const short* src = G + (grow0 + r) * K + k0 + (gcb >> 1);
        __builtin_amdgcn_global_load_lds(
            (const __attribute__((address_space(1))) void*)(const void*)src,
            (__attribute__((address_space(3))) void*)(void*)dst, 16, 0, 0);
    }
}

#define LOAD_A(T, grp) do {                                        \
    _Pragma("unroll") for (int _m = 0; _m < 4; ++_m) {             \
        const int _row = abase + (grp)*64 + _m*16 + l15;           \
        a[_m][0] = lds_frag(T, _row, l4b);                         \
        a[_m][1] = lds_frag(T, _row, 64 + l4b);                    \
    } } while (0)

#define LOAD_B(T, n0) do {                                         \
    _Pragma("unroll") for (int _n = 0; _n < 2; ++_n) {             \
        const int _row = bbase + ((n0)+_n)*16 + l15;               \
        b[(n0)+_n][0] = lds_frag(T, _row, l4b);                    \
        b[(n0)+_n][1] = lds_frag(T, _row, 64 + l4b);               \
    } } while (0)

#define MFMA16(MB, NB) do {                                                        \
    __builtin_amdgcn_s_setprio(1);                                                 \
    _Pragma("unroll") for (int _m = 0; _m < 4; ++_m)                               \
    _Pragma("unroll") for (int _n = 0; _n < 2; ++_n) {                             \
        acc[(MB)+_m][(NB)+_n] = __builtin_amdgcn_mfma_f32_16x16x32_bf16(           \
            a[_m][0], b[(NB)+_n][0], acc[(MB)+_m][(NB)+_n], 0, 0, 0);              \
        acc[(MB)+_m][(NB)+_n] = __builtin_amdgcn_mfma_f32_16x16x32_bf16(           \
            a[_m][1], b[(NB)+_n][1], acc[(MB)+_m][(NB)+_n], 0, 0, 0);              \
    }                                                                              \
    __builtin_amdgcn_s_setprio(0);                                                 \
} while (0)

template<int EPI, int KS>
__global__ __launch_bounds__(512, 2)
void gemm8(const short* __restrict__ A, const short* __restrict__ W,
           float* __restrict__ Cf, short* __restrict__ Cb,
           int N, int K)
{
    __shared__ __align__(16) short As[2][16384];
    __shared__ __align__(16) short Bs[2][16384];

    const int tid  = threadIdx.x;
    const int lane = tid & 63;
    const int wv   = tid >> 6;
    const int wm   = wv >> 2;
    const int wn   = wv & 3;
    const int l15  = lane & 15;
    const int l4b  = (lane >> 4) << 4;

    // XCD swizzle; within an XCD: 8 consecutive blocks share one (bx,kz) panel
    const int gx   = gridDim.x;
    const int nwg  = gx * 8 * KS;
    const int cpx  = nwg >> 3;
    const int orig = (blockIdx.z * 8 + blockIdx.y) * gx + blockIdx.x;
    const int lgc  = (orig & 7) * cpx + (orig >> 3);
    const int by   = lgc & 7;
    const int tq   = lgc >> 3;
    const int kz   = (KS == 1) ? 0 : (tq % KS);
    const int bx   = (KS == 1) ? tq : (tq / KS);

    const long row0 = (long)by << 8;
    const long col0 = (long)bx << 8;
    const int abase = wm << 7;
    const int bbase = wn << 6;

    const int  Kc    = K / KS;
    const long kbase = (long)kz * Kc;
    const int  iters = Kc >> 7;

    f32x4 acc[8][4];
#pragma unroll
    for (int i = 0; i < 8; ++i)
#pragma unroll
        for (int j = 0; j < 4; ++j) acc[i][j] = (f32x4){0.f,0.f,0.f,0.f};

    bf16x8 a[4][2], b[4][2];

    // prologue: stage buf0 (tile0) then buf1 (tile1)
    stage_half(A, row0,       K, kbase,      &As[0][0],    wv, lane);
    stage_half(A, row0 + 128, K, kbase,      &As[0][8192], wv, lane);
    stage_half(W, col0,       K, kbase,      &Bs[0][0],    wv, lane);
    stage_half(W, col0 + 128, K, kbase,      &Bs[0][8192], wv, lane);
    stage_half(A, row0,       K, kbase + 64, &As[1][0],    wv, lane);
    stage_half(A, row0 + 128, K, kbase + 64, &As[1][8192], wv, lane);
    stage_half(W, col0,       K, kbase + 64, &Bs[1][0],    wv, lane);
    stage_half(W, col0 + 128, K, kbase + 64, &Bs[1][8192], wv, lane);
    VMW(8);
    BAR();

#pragma unroll 1
    for (int it = 0; it < iters; ++it) {
        const long k2 = kbase + ((long)(2*it + 2) << 6);
        const long k3 = k2 + 64;
        const bool pf = (it + 1 < iters);

        // ---------------- tile 2it (buf0) ----------------
        // P1
        LOAD_A(As[0], 0); LOAD_B(Bs[0], 0);
        BAR(); LGKM0(); MFMA16(0, 0); BAR();
        // P2
        LOAD_B(Bs[0], 2);
        BAR(); LGKM0(); MFMA16(0, 2); BAR();
        // P3
        LOAD_A(As[0], 1);
        if (pf) stage_half(W, col0, K, k2, &Bs[0][0], wv, lane);
        BAR(); LGKM0(); MFMA16(4, 0); BAR();
        // P4
        if (pf) {
            stage_half(A, row0,       K, k2, &As[0][0],    wv, lane);
            stage_half(W, col0 + 128, K, k2, &Bs[0][8192], wv, lane);
        }
        VMW(6);
        BAR(); MFMA16(4, 2); BAR();

        // ---------------- tile 2it+1 (buf1) ----------------
        // P5
        LOAD_A(As[1], 0); LOAD_B(Bs[1], 0);
        if (pf) stage_half(A, row0 + 128, K, k2, &As[0][8192], wv, lane);
        BAR(); LGKM0(); MFMA16(0, 0); BAR();
        // P6
        LOAD_B(Bs[1], 2);
        BAR(); LGKM0(); MFMA16(0, 2); BAR();
        // P7
        LOAD_A(As[1], 1);
        if (pf) {
            stage_half(W, col0,       K, k3, &Bs[1][0],    wv, lane);
            stage_half(W, col0 + 128, K, k3, &Bs[1][8192], wv, lane);
        }
        BAR(); LGKM0(); MFMA16(4, 0); BAR();
        // P8
        if (pf) {
            stage_half(A, row0,       K, k3, &As[1][0],    wv, lane);
            stage_half(A, row0 + 128, K, k3, &As[1][8192], wv, lane);
        }
        VMW(8);
        BAR(); MFMA16(4, 2); BAR();
    }

    if (EPI == 0) {
        float* Cfp = Cf + ((KS > 1) ? (long)kz * ((long)N << 11) : 0);
#pragma unroll
        for (int m = 0; m < 8; ++m) {
#pragma unroll
            for (int n = 0; n < 4; ++n) {
                const long gr = row0 + (wm << 7) + m*16 + ((lane >> 4) << 2);
                const long gc = col0 + (wn << 6) + n*16 + l15;
#pragma unroll
                for (int r = 0; r < 4; ++r)
                    Cfp[(gr + r) * N + gc] = acc[m][n][r];
            }
        }
    } else {
#pragma unroll
        for (int m = 0; m < 8; ++m) {
#pragma unroll
            for (int n = 0; n < 4; ++n) {
                const long gr = row0 + (wm << 7) + m*16 + ((lane >> 4) << 2);
                const long gc = col0 + (wn << 6) + n*16 + l15;
#pragma unroll
                for (int r = 0; r < 4; ++r)
                    Cb[(gr + r) * N + gc] = f2bs(acc[m][n][r]);
            }
        }
    }
}

// ---------------------------------------------------------------------------
// RoPE (single qkv buffer, R8-proven)
// ---------------------------------------------------------------------------
__global__ __launch_bounds__(128)
void rope_kernel(const int* __restrict__ pos, const float* __restrict__ qkv,
                 short* __restrict__ Qo, short* __restrict__ Ko)
{
    const int h = blockIdx.x;
    const int s = blockIdx.y;
    const int d = threadIdx.x;
    const int j = d & 63;
    const float p = (float)pos[s];
    const float invf = __expf((float)j * -0.20503692895f);  // ln(5e5)/64
    float sn, cs;
    __sincosf(p * invf, &sn, &cs);
    const long base = (long)s * 6144 + h * 128;
    const float x1 = qkv[base + j];
    const float x2 = qkv[base + 64 + j];
    const float outv = (d < 64) ? (x1 * cs - x2 * sn) : (x2 * cs + x1 * sn);
    const short ob = f2bs(outv);
    if (h < 32) Qo[(long)s * 4096 + h * 128 + d] = ob;
    else        Ko[(long)s * 1024 + (h - 32) * 128 + d] = ob;
}

// ---------------------------------------------------------------------------
// V transpose: qkv f32 v-part [S,8,128] -> Vt bf16 [8][128][S]
// ---------------------------------------------------------------------------
__global__ __launch_bounds__(256)
void vtrans_kernel(const float* __restrict__ qkv, short* __restrict__ Vt)
{
    __shared__ short tile[64][136];
    const int tid = threadIdx.x;
    const int s0 = blockIdx.x << 6;
    const int h = blockIdx.y;
    {
        const int srow = tid >> 2;
        const int c0 = (tid & 3) << 5;
        const float* src = qkv + (long)(s0 + srow) * 6144 + 5120 + h * 128 + c0;
#pragma unroll
        for (int m = 0; m < 8; ++m) {
            f32x4 f = *(const f32x4*)(src + (m << 2));
            tile[srow][c0 + (m << 2) + 0] = f2bs(f[0]);
            tile[srow][c0 + (m << 2) + 1] = f2bs(f[1]);
            tile[srow][c0 + (m << 2) + 2] = f2bs(f[2]);
            tile[srow][c0 + (m << 2) + 3] = f2bs(f[3]);
        }
    }
    __syncthreads();
    {
        const int d = tid >> 1;
        const int sc = (tid & 1) << 5;
        short* dst = Vt + ((long)h * 128 + d) * 2048 + s0 + sc;
#pragma unroll
        for (int m = 0; m < 4; ++m) {
            bf16x8 v;
#pragma unroll
            for (int e = 0; e < 8; ++e) v[e] = tile[sc + (m << 3) + e][d];
            *(bf16x8*)(dst + (m << 3)) = v;
        }
    }
}

// ---------------------------------------------------------------------------
// Flash attention (causal, GQA rep=4).  QBLK=128 (8 waves x 16 q-rows),
// KVBLK=64.  Grid (8, 32): block bx processes q-chunks {bx, 15-bx} -> every
// block does exactly 34 KV-tile iterations (perfect causal balance).
// K/V staging serves 2x the q-rows of the old QBLK=64 version; barriers/elem
// halved.  T5 setprio around MFMA clusters (independent blocks regime, m191).
// ---------------------------------------------------------------------------
__global__ __launch_bounds__(512)
void flash_kernel(const short* __restrict__ Qg, const short* __restrict__ Kg,
                  const short* __restrict__ Vtg, short* __restrict__ Ctx)
{
    __shared__ short Qs[128 * 128];   // 32 KiB
    __shared__ short Ks[64 * 128];    // 16 KiB
    __shared__ short Vs[128 * 64];    // 16 KiB
    __shared__ short Ps[8 * 16 * 64]; // 16 KiB

    const int tid  = threadIdx.x;
    const int lane = tid & 63;
    const int wv   = tid >> 6;          // 0..7
    const int l15  = lane & 15;
    const int l4e  = (lane >> 4) << 3;
    const int head = blockIdx.y;
    const int kvh  = head >> 2;

#pragma unroll 1
    for (int qc = 0; qc < 2; ++qc) {
        const int qt = qc ? (15 - (int)blockIdx.x) : (int)blockIdx.x;
        const int q0 = qt << 7;

        __syncthreads();   // guard Qs vs previous chunk's readers
        {   // stage Q (swizzled): 128 rows x 128 cols
            const int row = tid >> 2;
            const int c0 = (tid & 3) << 5;
            const short* src = Qg + (long)(q0 + row) * 4096 + head * 128 + c0;
            const int sw = (row & 7) << 3;
#pragma unroll
            for (int m = 0; m < 4; ++m) {
                bf16x8 v = *(const bf16x8*)(src + (m << 3));
                *(bf16x8*)&Qs[row * 128 + ((c0 + (m << 3)) ^ sw)] = v;
            }
        }

        float mrow[4], lrow[4];
        f32x4 o[8];
#pragma unroll
        for (int r = 0; r < 4; ++r) { mrow[r] = -__builtin_inff(); lrow[r] = 0.f; }
#pragma unroll
        for (int d = 0; d < 8; ++d) o[d] = (f32x4){0.f,0.f,0.f,0.f};

        const int ntiles = (qt << 1) + 2;
#pragma unroll 1
        for (int t = 0; t < ntiles; ++t) {
            const int kv0 = t << 6;
            __syncthreads();
            {   // stage K: 64 rows x 128 cols (512 thr: 2 bf16x8 each)
                const int row = tid >> 3;
                const int c0 = (tid & 7) << 4;
                const short* src = Kg + (long)(kv0 + row) * 1024 + kvh * 128 + c0;
                const int sw = (row & 7) << 3;
#pragma unroll
                for (int m = 0; m < 2; ++m) {
                    bf16x8 v = *(const bf16x8*)(src + (m << 3));
                    *(bf16x8*)&Ks[row * 128 + ((c0 + (m << 3)) ^ sw)] = v;
                }
            }
            {   // stage Vt: 128 d-rows x 64 s-cols
                const int d = tid >> 2;
                const int sc = (tid & 3) << 4;
                const short* src = Vtg + ((long)kvh * 128 + d) * 2048 + kv0 + sc;
                const int sw = (d & 7) << 3;
#pragma unroll
                for (int m = 0; m < 2; ++m) {
                    bf16x8 v = *(const bf16x8*)(src + (m << 3));
                    *(bf16x8*)&Vs[d * 64 + ((sc + (m << 3)) ^ sw)] = v;
                }
            }
            __syncthreads();

            bf16x8 qa[4];
            {
                const int qrow = (wv << 4) + l15;
                const int sw = (qrow & 7) << 3;
#pragma unroll
                for (int kk = 0; kk < 4; ++kk)
                    qa[kk] = *(const bf16x8*)&Qs[qrow * 128 + ((l4e + (kk << 5)) ^ sw)];
            }
            f32x4 sacc[4];
            __builtin_amdgcn_s_setprio(1);
#pragma unroll
            for (int j = 0; j < 4; ++j) {
                sacc[j] = (f32x4){0.f,0.f,0.f,0.f};
                const int krow = (j << 4) + l15;
                const int sw = (krow & 7) << 3;
#pragma unroll
                for (int kk = 0; kk < 4; ++kk) {
                    bf16x8 kb8 = *(const bf16x8*)&Ks[krow * 128 + ((l4e + (kk << 5)) ^ sw)];
                    sacc[j] = __builtin_amdgcn_mfma_f32_16x16x32_bf16(qa[kk], kb8, sacc[j], 0, 0, 0);
                }
            }
            __builtin_amdgcn_s_setprio(0);

#pragma unroll
            for (int ri = 0; ri < 4; ++ri) {
                const int grow = q0 + (wv << 4) + ((lane >> 4) << 2) + ri;
                float sv[4];
#pragma unroll
                for (int j = 0; j < 4; ++j) {
                    float s = sacc[j][ri] * SCALE_ATTN;
                    const int col = kv0 + (j << 4) + l15;
                    sv[j] = (col > grow) ? -1e30f : s;
                }
                float mx = fmaxf(fmaxf(sv[0], sv[1]), fmaxf(sv[2], sv[3]));
#pragma unroll
                for (int dd = 1; dd < 16; dd <<= 1) mx = fmaxf(mx, __shfl_xor(mx, dd));
                const float mnew = fmaxf(mrow[ri], mx);
                const float alpha = __expf(mrow[ri] - mnew);
                mrow[ri] = mnew;
                float psum = 0.f;
                short pb[4];
#pragma unroll
                for (int j = 0; j < 4; ++j) {
                    float p = __expf(sv[j] - mnew);
                    psum += p;
                    pb[j] = f2bs(p);
                }
                lrow[ri] = lrow[ri] * alpha + psum;
#pragma unroll
                for (int d = 0; d < 8; ++d) o[d][ri] *= alpha;
                const int prow = ((lane >> 4) << 2) + ri;
                const int sw = (prow & 7) << 3;
#pragma unroll
                for (int j = 0; j < 4; ++j)
                    Ps[(wv << 10) + prow * 64 + ((((j << 4) + l15)) ^ sw)] = pb[j];
            }

            bf16x8 pa0, pa1;
            {
                const int prow = l15;
                const int sw = (prow & 7) << 3;
                pa0 = *(const bf16x8*)&Ps[(wv << 10) + prow * 64 + (l4e ^ sw)];
                pa1 = *(const bf16x8*)&Ps[(wv << 10) + prow * 64 + ((l4e + 32) ^ sw)];
            }
            __builtin_amdgcn_s_setprio(1);
#pragma unroll
            for (int fd = 0; fd < 8; ++fd) {
                const int drow = (fd << 4) + l15;
                const int sw = (drow & 7) << 3;
                bf16x8 v0 = *(const bf16x8*)&Vs[drow * 64 + (l4e ^ sw)];
                bf16x8 v1 = *(const bf16x8*)&Vs[drow * 64 + ((l4e + 32) ^ sw)];
                o[fd] = __builtin_amdgcn_mfma_f32_16x16x32_bf16(pa0, v0, o[fd], 0, 0, 0);
                o[fd] = __builtin_amdgcn_mfma_f32_16x16x32_bf16(pa1, v1, o[fd], 0, 0, 0);
            }
            __builtin_amdgcn_s_setprio(0);
        }

        float inv[4];
#pragma unroll
        for (int ri = 0; ri < 4; ++ri) {
            float ls = lrow[ri];
#pragma unroll
            for (int dd = 1; dd < 16; dd <<= 1) ls += __shfl_xor(ls, dd);
            inv[ri] = 1.0f / ls;
        }
#pragma unroll
        for (int fd = 0; fd < 8; ++fd)
#pragma unroll
            for (int ri = 0; ri < 4; ++ri) {
                const long row = q0 + (wv << 4) + ((lane >> 4) << 2) + ri;
                Ctx[row * 4096 + head * 128 + (fd << 4) + l15] = f2bs(o[fd][ri] * inv[ri]);
            }
    }
}

// ---------------------------------------------------------------------------
extern "C" void kernel_launch(void* const* d_in, const int* in_sizes, int n_in,
                              void* d_out, int out_size, void* d_ws, size_t ws_size,
                              hipStream_t stream)
{
    const int*   positions = (const int*)d_in[0];
    const float* hidden    = (const float*)d_in[1];
    const float* residual  = (const float*)d_in[2];
    const float* w_qkv     = (const float*)d_in[3];
    const float* w_o       = (const float*)d_in[4];
    const float* w_gu      = (const float*)d_in[5];
    const float* w_down    = (const float*)d_in[6];
    const float* w_ln1     = (const float*)d_in[7];
    const float* w_ln2     = (const float*)d_in[8];

    float* out_f   = (float*)d_out;              // [2048,4096] final output
    float* resid2  = out_f + 8388608;            // [2048,4096] residual output
    float* resid1  = out_f;                      // scratch: dead before add2 writes

    char* wsb = (char*)d_ws;
    short* h1     = (short*)(wsb + 0);           // 16 MiB (dead after qkv gemm)
    short* ctx    = (short*)(wsb + 0);           // reuse (dead after o gemm)
    float* qkvbuf = (float*)(wsb + 16777216);    // 48 MiB f32 (16..64, dead after rope/vtrans)
    short* h2     = (short*)(wsb + 16777216);    // reuse (16..32, written at rms2)
    float* Po     = (float*)(wsb + 33554432);    // 2x32 MiB o partials (32..96, dead after rms2)
    short* qb     = (short*)(wsb + 117440512);   // 16 MiB (112..128, dead after flash)
    short* kb     = (short*)(wsb + 134217728);   //  4 MiB (128..132, dead after flash)
    short* vt     = (short*)(wsb + 138412032);   //  4 MiB (132..136, dead after flash)
    short* gu     = (short*)(wsb + 33554432);    // 112 MiB (32..144, over dead Po/qkvbuf/qb/kb/vt)
    short* hm     = (short*)(wsb + 150994944);   // 56 MiB (144..200)
    float* Pd     = (float*)(wsb + 0);           // 2x32 MiB down partials (0..64)
    short* wbuf   = (short*)(wsb + 209715200);   // 224 MiB bf16 weight slab (200..424)
    short* wbuf_o = wbuf + 25165824;             // o weights at slab+48 MiB (coexist w/ qkv weights)

    // 1. residual1 = hidden + residual ; h1 = rmsnorm(residual1)
    add_rmsnorm_kernel<<<2048, 256, 0, stream>>>(hidden, nullptr, residual, w_ln1, resid1, h1);
    // 2. qkv (KS=1, R8-proven)
    wconv_kernel<<<2048, 256, 0, stream>>>(w_qkv, wbuf, 3145728L);
    gemm8<0,1><<<dim3(24, 8, 1), 512, 0, stream>>>(h1, wbuf, qkvbuf, nullptr, 6144, 4096);
    // 3. o weights early (writeback settles during rope/vtrans/flash)
    wconv_kernel<<<2048, 256, 0, stream>>>(w_o, wbuf_o, 2097152L);
    // 4-5. RoPE + V transpose
    rope_kernel<<<dim3(40, 2048), 128, 0, stream>>>(positions, qkvbuf, qb, kb);
    vtrans_kernel<<<dim3(32, 8), 256, 0, stream>>>(qkvbuf, vt);
    // 6. flash attention (QBLK=128, balanced causal pairing)
    flash_kernel<<<dim3(8, 32), 512, 0, stream>>>(qb, kb, vt, ctx);
    // 7. o-proj (2-way K-split partials)
    gemm8<0,2><<<dim3(16, 8, 2), 512, 0, stream>>>(ctx, wbuf_o, Po, nullptr, 4096, 4096);
    // 8. residual2 = Po0+Po1+residual1 ; h2 = rmsnorm(residual2)
    add_rmsnorm_kernel<<<2048, 256, 0, stream>>>(Po, Po + 8388608, resid1, w_ln2, resid2, h2);
    // 9. gate_up -> gu bf16 [2048][28672]  (EPI2, R8-proven)
    wconv_kernel<<<2048, 256, 0, stream>>>(w_gu, wbuf, 14680064L);
    gemm8<2,1><<<dim3(112, 8, 1), 512, 0, stream>>>(h2, wbuf, nullptr, gu, 28672, 4096);
    // 10. hm = silu(gate)*up
    silu_kernel<<<dim3(7, 2048), 256, 0, stream>>>(gu, hm);
    // 11. down (2-way K-split partials) ; out = Pd0+Pd1
    wconv_kernel<<<2048, 256, 0, stream>>>(w_down, wbuf, 7340032L);
    gemm8<0,2><<<dim3(16, 8, 2), 512, 0, stream>>>(hm, wbuf, Pd, nullptr, 4096, 14336);
    add2_kernel<<<2048, 256, 0, stream>>>(Pd, Pd + 8388608, out_f, 2097152L);
}